// Round 1
// baseline (1521.061 us; speedup 1.0000x reference)
//
#include <hip/hip_runtime.h>
#include <math.h>

#define N_NODES 500000
#define HIDDEN  512
#define GOALD   128
#define INDIM   640   // HIDDEN + GOALD
#define NSEG    512
#define BLK     256
#define MROWS   2
#define NODES_PER_BLK (BLK * MROWS)  // 512

// ---------------------------------------------------------------------------
// Kernel 1: per-node MLP.  out[n] = b2 + sum_j relu( (x @ W1 + b1)[j] ) * W2[j]
// Thread handles MROWS=2 nodes (rows n0 = blk*512 + tid, n1 = n0 + 256).
// W1 (640x16 = 40 KB) staged in LDS once per block; reads are wave-uniform
// (broadcast, conflict-free).  x rows streamed as 64 B chunks (4 x float4)
// so each HBM line is fully consumed from registers immediately.
// ---------------------------------------------------------------------------

__device__ __forceinline__ void chunk_fma(const float* __restrict__ wbase,
                                          const float4 a0[4], const float4 a1[4],
                                          float acc0[16], float acc1[16]) {
#pragma unroll
  for (int kk = 0; kk < 16; ++kk) {
    const float4* wr = (const float4*)(wbase + kk * 16);
    const float x0 = ((const float*)&a0[kk >> 2])[kk & 3];
    const float x1 = ((const float*)&a1[kk >> 2])[kk & 3];
#pragma unroll
    for (int j4 = 0; j4 < 4; ++j4) {
      float4 w = wr[j4];
      acc0[4 * j4 + 0] = fmaf(x0, w.x, acc0[4 * j4 + 0]);
      acc0[4 * j4 + 1] = fmaf(x0, w.y, acc0[4 * j4 + 1]);
      acc0[4 * j4 + 2] = fmaf(x0, w.z, acc0[4 * j4 + 2]);
      acc0[4 * j4 + 3] = fmaf(x0, w.w, acc0[4 * j4 + 3]);
      acc1[4 * j4 + 0] = fmaf(x1, w.x, acc1[4 * j4 + 0]);
      acc1[4 * j4 + 1] = fmaf(x1, w.y, acc1[4 * j4 + 1]);
      acc1[4 * j4 + 2] = fmaf(x1, w.z, acc1[4 * j4 + 2]);
      acc1[4 * j4 + 3] = fmaf(x1, w.w, acc1[4 * j4 + 3]);
    }
  }
}

template <int NCHUNK>
__device__ __forceinline__ void mlp_phase(const float4* __restrict__ x0p,
                                          const float4* __restrict__ x1p,
                                          const float* __restrict__ wbase,
                                          float acc0[16], float acc1[16]) {
  for (int c = 0; c < NCHUNK; ++c) {
    float4 a0[4], a1[4];
#pragma unroll
    for (int q = 0; q < 4; ++q) {
      a0[q] = x0p[c * 4 + q];
      a1[q] = x1p[c * 4 + q];
    }
    chunk_fma(wbase + c * 256, a0, a1, acc0, acc1);
  }
}

__global__ __launch_bounds__(BLK, 4)
void mlp_kernel(const float* __restrict__ nodes, const float* __restrict__ goal,
                const float* __restrict__ W1, const float* __restrict__ b1,
                const float* __restrict__ W2, const float* __restrict__ b2,
                float* __restrict__ out) {
  __shared__ __align__(16) float w1s[INDIM * 16];  // 40 KB -> 4 blocks/CU
  for (int i = threadIdx.x; i < INDIM * 16 / 4; i += BLK)
    ((float4*)w1s)[i] = ((const float4*)W1)[i];
  __syncthreads();

  const int n0 = blockIdx.x * NODES_PER_BLK + threadIdx.x;
  const int n1 = n0 + BLK;
  const bool v0 = n0 < N_NODES;
  const bool v1 = n1 < N_NODES;
  const int r0 = v0 ? n0 : 0;
  const int r1 = v1 ? n1 : 0;

  const float4* xr0 = (const float4*)(nodes + (size_t)r0 * HIDDEN);
  const float4* xr1 = (const float4*)(nodes + (size_t)r1 * HIDDEN);
  const float4* gr0 = (const float4*)(goal + (size_t)r0 * GOALD);
  const float4* gr1 = (const float4*)(goal + (size_t)r1 * GOALD);

  float acc0[16], acc1[16];
#pragma unroll
  for (int j = 0; j < 16; ++j) {
    float bv = b1[j];
    acc0[j] = bv;
    acc1[j] = bv;
  }

  // HIDDEN: 512 floats = 32 chunks of 16; GOAL: 128 floats = 8 chunks
  mlp_phase<32>(xr0, xr1, w1s, acc0, acc1);
  mlp_phase<8>(gr0, gr1, w1s + HIDDEN * 16, acc0, acc1);

  float o0 = b2[0], o1 = o0;
#pragma unroll
  for (int j = 0; j < 16; ++j) {
    float w = W2[j];
    o0 = fmaf(fmaxf(acc0[j], 0.f), w, o0);
    o1 = fmaf(fmaxf(acc1[j], 0.f), w, o1);
  }
  if (v0) out[n0] = o0;
  if (v1) out[n1] = o1;
}

// ---------------------------------------------------------------------------
// Kernel 2: per-segment mean & max (segment_ids sorted).  One block/segment.
// ---------------------------------------------------------------------------

__device__ __forceinline__ int lower_bound_seg(const int* __restrict__ ids, int n, int key) {
  int lo = 0, hi = n;
  while (lo < hi) {
    int mid = (lo + hi) >> 1;
    if (ids[mid] < key) lo = mid + 1; else hi = mid;
  }
  return lo;
}

__global__ __launch_bounds__(256)
void seg_kernel(const float* __restrict__ vals, const int* __restrict__ ids,
                float* __restrict__ out) {
  const int s = blockIdx.x;
  const int lo = lower_bound_seg(ids, N_NODES, s);
  const int hi = lower_bound_seg(ids, N_NODES, s + 1);

  float sum = 0.f, mx = -INFINITY;
  for (int i = lo + threadIdx.x; i < hi; i += 256) {
    float v = vals[i];
    sum += v;
    mx = fmaxf(mx, v);
  }
#pragma unroll
  for (int off = 32; off > 0; off >>= 1) {
    sum += __shfl_down(sum, off, 64);
    mx = fmaxf(mx, __shfl_down(mx, off, 64));
  }
  __shared__ float s_sum[4], s_max[4];
  const int wave = threadIdx.x >> 6;
  const int lane = threadIdx.x & 63;
  if (lane == 0) { s_sum[wave] = sum; s_max[wave] = mx; }
  __syncthreads();
  if (threadIdx.x == 0) {
    float ts = 0.f, tm = -INFINITY;
#pragma unroll
    for (int w = 0; w < 4; ++w) { ts += s_sum[w]; tm = fmaxf(tm, s_max[w]); }
    const int cnt = hi - lo;
    const float mean = ts / fmaxf((float)cnt, 1.0f);
    out[s] = 0.5f * tm + 0.5f * mean;
  }
}

extern "C" void kernel_launch(void* const* d_in, const int* in_sizes, int n_in,
                              void* d_out, int out_size, void* d_ws, size_t ws_size,
                              hipStream_t stream) {
  const float* nodes = (const float*)d_in[0];
  const float* goal  = (const float*)d_in[1];
  const int*   seg   = (const int*)d_in[2];
  // d_in[3] = num_segments (known constant 512)
  const float* W1 = (const float*)d_in[4];
  const float* b1 = (const float*)d_in[5];
  const float* W2 = (const float*)d_in[6];
  const float* b2 = (const float*)d_in[7];
  float* out = (float*)d_out;
  float* tmp = (float*)d_ws;  // 500000 floats = 2 MB scratch for per-node MLP output

  const int blocks = (N_NODES + NODES_PER_BLK - 1) / NODES_PER_BLK;  // 977
  mlp_kernel<<<blocks, BLK, 0, stream>>>(nodes, goal, W1, b1, W2, b2, tmp);
  seg_kernel<<<NSEG, 256, 0, stream>>>(tmp, seg, out);
}